// Round 3
// 678.512 us; speedup vs baseline: 1.1061x; 1.1061x over previous
//
#include <hip/hip_runtime.h>
#include <hip/hip_bf16.h>

typedef __attribute__((ext_vector_type(8))) __bf16 bf16x8;
typedef __attribute__((ext_vector_type(4))) float floatx4;

#define S_LEN 4096
#define NBH   64
#define BM    256   // q rows per block (8 waves x 32)
#define NW    8     // waves per block
#define BN    64    // keys per tile
#define KSTR  72    // padded key/V^T row stride (shorts)
#define PSTR  72    // padded P row stride (shorts)
#define C_SCALE 0.18033688011112042f  // log2(e) / sqrt(64)

__device__ __forceinline__ short f2bf(float x) {
  __hip_bfloat16 h = __float2bfloat16(x);
  return *reinterpret_cast<const short*>(&h);
}

// Single-launch kernel, structurally identical to the verified BM=128 baseline
// (one launch, static LDS, no workspace). BM=256 with 8 waves halves the
// per-element staging cost (global read + f32->bf16 cvt + LDS write) and the
// barrier count per unit of compute; per-wave compute code is unchanged.
__global__ __launch_bounds__(512)
void mea_fwd(const float* __restrict__ qp, const float* __restrict__ kp,
             const float* __restrict__ vp, const int* __restrict__ cm,
             float* __restrict__ op)
{
  __shared__ short kL[BN * KSTR];         // K tile  [key][d]   (bf16)
  __shared__ short vT[64 * KSTR];         // V^T     [d][key]   (bf16, key col rotated by (d>>4)*16)
  __shared__ short pL[NW * 32 * PSTR];    // P per wave [q_local][key] (bf16)

  const int t    = threadIdx.x;
  const int w    = t >> 6;
  const int lane = t & 63;
  const int lg   = lane >> 4;
  const int l16  = lane & 15;

  const int bh  = blockIdx.y;
  const int qt  = (int)(gridDim.x - 1) - (int)blockIdx.x;  // big blocks first
  const int q0  = qt * BM;
  const int qw0 = q0 + w * 32;            // this wave's first q row
  const long base = (long)bh * S_LEN * 64;
  const int causal = cm[0];

  // staging split across 512 threads: 8 elems (one key-row slice) per thread
  const int skr = t >> 3;                 // key row (0..63)
  const int sd0 = (t & 7) * 8;            // first d (0,8,...,56)
  const int svcol = (skr + (sd0 >> 4) * 16) & 63;  // rotated key column for V^T

  // Q as B-fragments with softmax scale folded in:
  // B[k=d][n=q]; lane holds q = qw0+nt*16+l16, d = ks*32+lg*8+j
  bf16x8 qfrag[2][2];
#pragma unroll
  for (int nt = 0; nt < 2; ++nt)
#pragma unroll
    for (int ks = 0; ks < 2; ++ks) {
      const float* qr = qp + base + (long)(qw0 + nt*16 + l16) * 64 + ks*32 + lg*8;
      float4 a = *(const float4*)(qr);
      float4 b = *(const float4*)(qr + 4);
      union { short s[8]; bf16x8 v; } u;
      u.s[0]=f2bf(a.x*C_SCALE); u.s[1]=f2bf(a.y*C_SCALE);
      u.s[2]=f2bf(a.z*C_SCALE); u.s[3]=f2bf(a.w*C_SCALE);
      u.s[4]=f2bf(b.x*C_SCALE); u.s[5]=f2bf(b.y*C_SCALE);
      u.s[6]=f2bf(b.z*C_SCALE); u.s[7]=f2bf(b.w*C_SCALE);
      qfrag[nt][ks] = u.v;
    }

  floatx4 oacc[2][4];
#pragma unroll
  for (int i = 0; i < 2; ++i)
#pragma unroll
    for (int j = 0; j < 4; ++j)
      oacc[i][j] = (floatx4){0.f, 0.f, 0.f, 0.f};

  float m_run[2] = {-__builtin_inff(), -__builtin_inff()};
  float l_run[2] = {0.f, 0.f};

  const int kmax   = causal ? (q0 + BM) : S_LEN;
  const int ntiles = kmax / BN;

  // ---- prefetch tile 0 into registers ----
  float4 kpre[2], vpre[2];
  {
    const float* kb = kp + base + (long)skr * 64 + sd0;
    kpre[0] = ((const float4*)kb)[0];
    kpre[1] = ((const float4*)kb)[1];
    const float* vb = vp + base + (long)skr * 64 + sd0;
    vpre[0] = ((const float4*)vb)[0];
    vpre[1] = ((const float4*)vb)[1];
  }

  for (int kt = 0; kt < ntiles; ++kt) {
    const int k0 = kt * BN;

    // ---- store prefetched regs -> LDS (cvt f32->bf16) ----
    {
      union { short s[8]; uint4 u; } pk;
      pk.s[0]=f2bf(kpre[0].x); pk.s[1]=f2bf(kpre[0].y);
      pk.s[2]=f2bf(kpre[0].z); pk.s[3]=f2bf(kpre[0].w);
      pk.s[4]=f2bf(kpre[1].x); pk.s[5]=f2bf(kpre[1].y);
      pk.s[6]=f2bf(kpre[1].z); pk.s[7]=f2bf(kpre[1].w);
      *(uint4*)(&kL[skr * KSTR + sd0]) = pk.u;

      short vs[8];
      vs[0]=f2bf(vpre[0].x); vs[1]=f2bf(vpre[0].y);
      vs[2]=f2bf(vpre[0].z); vs[3]=f2bf(vpre[0].w);
      vs[4]=f2bf(vpre[1].x); vs[5]=f2bf(vpre[1].y);
      vs[6]=f2bf(vpre[1].z); vs[7]=f2bf(vpre[1].w);
#pragma unroll
      for (int i = 0; i < 8; ++i)
        vT[(sd0 + i) * KSTR + svcol] = vs[i];
    }
    __syncthreads();   // staging visible to all waves

    // ---- issue next tile's global loads (consumed next iteration) ----
    if (kt + 1 < ntiles) {
      const int kn = k0 + BN;
      const float* kb = kp + base + (long)(kn + skr) * 64 + sd0;
      kpre[0] = ((const float4*)kb)[0];
      kpre[1] = ((const float4*)kb)[1];
      const float* vb = vp + base + (long)(kn + skr) * 64 + sd0;
      vpre[0] = ((const float4*)vb)[0];
      vpre[1] = ((const float4*)vb)[1];
    }

    if (!(causal && k0 >= qw0 + 32)) {   // tile not fully masked for this wave
      // ---- S^T = K * Q^T : C[row=key][col=q], already in log2 domain ----
      floatx4 sacc[4][2];
#pragma unroll
      for (int mt = 0; mt < 4; ++mt)
#pragma unroll
        for (int nt = 0; nt < 2; ++nt)
          sacc[mt][nt] = (floatx4){0.f, 0.f, 0.f, 0.f};
#pragma unroll
      for (int ks = 0; ks < 2; ++ks)
#pragma unroll
        for (int mt = 0; mt < 4; ++mt) {
          bf16x8 kfrag = *(const bf16x8*)(&kL[(mt*16 + l16) * KSTR + ks*32 + lg*8]);
#pragma unroll
          for (int nt = 0; nt < 2; ++nt)
            sacc[mt][nt] = __builtin_amdgcn_mfma_f32_16x16x32_bf16(kfrag, qfrag[nt][ks], sacc[mt][nt], 0, 0, 0);
        }

      // ---- online softmax (exp2 domain) ----
      const bool needmask = causal && (k0 + BN - 1 > qw0);
      float mnew[2] = {m_run[0], m_run[1]};
#pragma unroll
      for (int mt = 0; mt < 4; ++mt)
#pragma unroll
        for (int nt = 0; nt < 2; ++nt)
#pragma unroll
          for (int r = 0; r < 4; ++r) {
            float v = sacc[mt][nt][r];
            if (needmask) {
              int key = k0  + mt*16 + lg*4 + r;
              int q   = qw0 + nt*16 + l16;
              if (q < key) v = -__builtin_inff();
            }
            sacc[mt][nt][r] = v;
            mnew[nt] = fmaxf(mnew[nt], v);
          }
#pragma unroll
      for (int nt = 0; nt < 2; ++nt) {
        mnew[nt] = fmaxf(mnew[nt], __shfl_xor(mnew[nt], 16));
        mnew[nt] = fmaxf(mnew[nt], __shfl_xor(mnew[nt], 32));
      }
      float alpha[2], rsum[2];
#pragma unroll
      for (int nt = 0; nt < 2; ++nt) {
        alpha[nt] = __builtin_amdgcn_exp2f(m_run[nt] - mnew[nt]);  // first tile: exp2(-inf)=0
        m_run[nt] = mnew[nt];
        rsum[nt]  = 0.f;
      }
      // exp, row-sum, pack P (4 consecutive keys/lane -> one b64 write)
#pragma unroll
      for (int mt = 0; mt < 4; ++mt)
#pragma unroll
        for (int nt = 0; nt < 2; ++nt) {
          union { short s[4]; uint2 u; } pk;
#pragma unroll
          for (int r = 0; r < 4; ++r) {
            float e = __builtin_amdgcn_exp2f(sacc[mt][nt][r] - mnew[nt]);
            rsum[nt] += e;
            pk.s[r] = f2bf(e);
          }
          *(uint2*)(&pL[(w*32 + nt*16 + l16) * PSTR + mt*16 + lg*4]) = pk.u;
        }
#pragma unroll
      for (int nt = 0; nt < 2; ++nt) {
        rsum[nt] += __shfl_xor(rsum[nt], 16);
        rsum[nt] += __shfl_xor(rsum[nt], 32);
        l_run[nt] = l_run[nt] * alpha[nt] + rsum[nt];
      }
      // rescale O accumulator (alpha from q=l16 layout to q=lg*4+r layout)
#pragma unroll
      for (int mo = 0; mo < 2; ++mo)
#pragma unroll
        for (int r = 0; r < 4; ++r) {
          float al = __shfl(alpha[mo], lg*4 + r);
#pragma unroll
          for (int nd = 0; nd < 4; ++nd)
            oacc[mo][nd][r] *= al;
        }

      // ---- O += P * V ----
#pragma unroll
      for (int ks = 0; ks < 2; ++ks) {
        bf16x8 vfrag[4];
#pragma unroll
        for (int nd = 0; nd < 4; ++nd) {
          int colr = (ks*32 + lg*8 + nd*16) & 63;   // match V^T rotation
          vfrag[nd] = *(const bf16x8*)(&vT[(nd*16 + l16) * KSTR + colr]);
        }
#pragma unroll
        for (int mo = 0; mo < 2; ++mo) {
          bf16x8 pfrag = *(const bf16x8*)(&pL[(w*32 + mo*16 + l16) * PSTR + ks*32 + lg*8]);
#pragma unroll
          for (int nd = 0; nd < 4; ++nd)
            oacc[mo][nd] = __builtin_amdgcn_mfma_f32_16x16x32_bf16(pfrag, vfrag[nd], oacc[mo][nd], 0, 0, 0);
        }
      }
    }

    __syncthreads();   // all waves done reading LDS before next store phase
  }

  // ---- epilogue: O / l, f32 out ----
#pragma unroll
  for (int mo = 0; mo < 2; ++mo)
#pragma unroll
    for (int r = 0; r < 4; ++r) {
      float lv  = __shfl(l_run[mo], lg*4 + r);
      float inv = __builtin_amdgcn_rcpf(lv);
      int qrow  = qw0 + mo*16 + lg*4 + r;
#pragma unroll
      for (int nd = 0; nd < 4; ++nd)
        op[base + (long)qrow * 64 + nd*16 + l16] = oacc[mo][nd][r] * inv;
    }
}

extern "C" void kernel_launch(void* const* d_in, const int* in_sizes, int n_in,
                              void* d_out, int out_size, void* d_ws, size_t ws_size,
                              hipStream_t stream) {
  const float* q = (const float*)d_in[0];
  const float* k = (const float*)d_in[1];
  const float* v = (const float*)d_in[2];
  const int*  cm = (const int*)d_in[3];
  float* o = (float*)d_out;
  dim3 grid(S_LEN / BM, NBH);
  mea_fwd<<<grid, dim3(512, 1, 1), 0, stream>>>(q, k, v, cm, o);
}

// Round 5
// 645.654 us; speedup vs baseline: 1.1624x; 1.0509x over previous
//
#include <hip/hip_runtime.h>
#include <hip/hip_bf16.h>

typedef __attribute__((ext_vector_type(8))) __bf16 bf16x8;
typedef __attribute__((ext_vector_type(4))) float floatx4;

#define S_LEN 4096
#define NBH   64
#define BM    256   // q rows per block (8 waves x 32)
#define NW    8     // waves per block
#define BN    64    // keys per tile
#define KSTR  72    // padded key/V^T row stride (shorts)
#define C_SCALE 0.18033688011112042f  // log2(e) / sqrt(64)

__device__ __forceinline__ short f2bf(float x) {
  __hip_bfloat16 h = __float2bfloat16(x);
  return *reinterpret_cast<const short*>(&h);
}

// Key-permutation trick: softmax+PV are invariant under any permutation of the
// 64 keys within a tile if V is permuted identically. The bit-shuffle
//   p(s) = 32*s4 + 16*s3 + 8*s2 + 4*s5 + (s&3)     (s = key slot in tile)
// maps the QK^T C-layout fragments EXACTLY onto the PV A-operand layout, so P
// never touches LDS (pfrag is a pure in-lane repack of the softmax output).
// pL (36 KB) is gone -> LDS 18.4 KB -> 3+ blocks/CU instead of 2.
__global__ __launch_bounds__(512)
void mea_fwd(const float* __restrict__ qp, const float* __restrict__ kp,
             const float* __restrict__ vp, const int* __restrict__ cm,
             float* __restrict__ op)
{
  __shared__ short kL[BN * KSTR];         // K tile  [key][d]   (bf16, natural order)
  __shared__ short vT[64 * KSTR];         // V^T     [d][pvslot] (bf16, key perm + d-rotation)

  const int t    = threadIdx.x;
  const int w    = t >> 6;
  const int lane = t & 63;
  const int lg   = lane >> 4;
  const int l16  = lane & 15;

  const int bh  = blockIdx.y;
  const int qt  = (int)(gridDim.x - 1) - (int)blockIdx.x;  // big blocks first
  const int q0  = qt * BM;
  const int qw0 = q0 + w * 32;            // this wave's first q row
  const long base = (long)bh * S_LEN * 64;
  const int causal = cm[0];

  // staging split across 512 threads: 8 elems (one key-row slice) per thread
  const int skr = t >> 3;                 // key row (0..63)
  const int sd0 = (t & 7) * 8;            // first d (0,8,...,56)
  // pvslot = bit-permuted key slot (see p(s) above)
  const int pcol = ((skr >> 4) & 1) * 32 + ((skr >> 3) & 1) * 16 +
                   ((skr >> 2) & 1) * 8  + ((skr >> 5) & 1) * 4 + (skr & 3);
  const int svcol = (pcol + (sd0 >> 4) * 16) & 63;  // + d-dependent bank rotation

  // Q as B-fragments with softmax scale folded in:
  // B[k=d][n=q]; lane holds q = qw0+nt*16+l16, d = ks*32+lg*8+j
  bf16x8 qfrag[2][2];
#pragma unroll
  for (int nt = 0; nt < 2; ++nt)
#pragma unroll
    for (int ks = 0; ks < 2; ++ks) {
      const float* qr = qp + base + (long)(qw0 + nt*16 + l16) * 64 + ks*32 + lg*8;
      float4 a = *(const float4*)(qr);
      float4 b = *(const float4*)(qr + 4);
      union { short s[8]; bf16x8 v; } u;
      u.s[0]=f2bf(a.x*C_SCALE); u.s[1]=f2bf(a.y*C_SCALE);
      u.s[2]=f2bf(a.z*C_SCALE); u.s[3]=f2bf(a.w*C_SCALE);
      u.s[4]=f2bf(b.x*C_SCALE); u.s[5]=f2bf(b.y*C_SCALE);
      u.s[6]=f2bf(b.z*C_SCALE); u.s[7]=f2bf(b.w*C_SCALE);
      qfrag[nt][ks] = u.v;
    }

  floatx4 oacc[2][4];
#pragma unroll
  for (int i = 0; i < 2; ++i)
#pragma unroll
    for (int j = 0; j < 4; ++j)
      oacc[i][j] = (floatx4){0.f, 0.f, 0.f, 0.f};

  float m_run[2] = {-__builtin_inff(), -__builtin_inff()};
  float l_run[2] = {0.f, 0.f};

  const int kmax   = causal ? (q0 + BM) : S_LEN;
  const int ntiles = kmax / BN;

  // ---- prefetch tile 0 into registers ----
  float4 kpre[2], vpre[2];
  {
    const float* kb = kp + base + (long)skr * 64 + sd0;
    kpre[0] = ((const float4*)kb)[0];
    kpre[1] = ((const float4*)kb)[1];
    const float* vb = vp + base + (long)skr * 64 + sd0;
    vpre[0] = ((const float4*)vb)[0];
    vpre[1] = ((const float4*)vb)[1];
  }

  for (int kt = 0; kt < ntiles; ++kt) {
    const int k0 = kt * BN;

    // ---- store prefetched regs -> LDS (cvt f32->bf16) ----
    {
      union { short s[8]; uint4 u; } pk;
      pk.s[0]=f2bf(kpre[0].x); pk.s[1]=f2bf(kpre[0].y);
      pk.s[2]=f2bf(kpre[0].z); pk.s[3]=f2bf(kpre[0].w);
      pk.s[4]=f2bf(kpre[1].x); pk.s[5]=f2bf(kpre[1].y);
      pk.s[6]=f2bf(kpre[1].z); pk.s[7]=f2bf(kpre[1].w);
      *(uint4*)(&kL[skr * KSTR + sd0]) = pk.u;

      short vs[8];
      vs[0]=f2bf(vpre[0].x); vs[1]=f2bf(vpre[0].y);
      vs[2]=f2bf(vpre[0].z); vs[3]=f2bf(vpre[0].w);
      vs[4]=f2bf(vpre[1].x); vs[5]=f2bf(vpre[1].y);
      vs[6]=f2bf(vpre[1].z); vs[7]=f2bf(vpre[1].w);
#pragma unroll
      for (int i = 0; i < 8; ++i)
        vT[(sd0 + i) * KSTR + svcol] = vs[i];
    }
    __syncthreads();   // staging visible to all waves

    // ---- issue next tile's global loads (consumed next iteration) ----
    if (kt + 1 < ntiles) {
      const int kn = k0 + BN;
      const float* kb = kp + base + (long)(kn + skr) * 64 + sd0;
      kpre[0] = ((const float4*)kb)[0];
      kpre[1] = ((const float4*)kb)[1];
      const float* vb = vp + base + (long)(kn + skr) * 64 + sd0;
      vpre[0] = ((const float4*)vb)[0];
      vpre[1] = ((const float4*)vb)[1];
    }

    if (!(causal && k0 >= qw0 + 32)) {   // tile not fully masked for this wave
      // ---- S^T = K * Q^T : C[row=key][col=q], already in log2 domain ----
      floatx4 sacc[4][2];
#pragma unroll
      for (int mt = 0; mt < 4; ++mt)
#pragma unroll
        for (int nt = 0; nt < 2; ++nt)
          sacc[mt][nt] = (floatx4){0.f, 0.f, 0.f, 0.f};
#pragma unroll
      for (int ks = 0; ks < 2; ++ks)
#pragma unroll
        for (int mt = 0; mt < 4; ++mt) {
          bf16x8 kfrag = *(const bf16x8*)(&kL[(mt*16 + l16) * KSTR + ks*32 + lg*8]);
#pragma unroll
          for (int nt = 0; nt < 2; ++nt)
            sacc[mt][nt] = __builtin_amdgcn_mfma_f32_16x16x32_bf16(kfrag, qfrag[nt][ks], sacc[mt][nt], 0, 0, 0);
        }

      // ---- online softmax (exp2 domain) ----
      const bool needmask = causal && (k0 + BN - 1 > qw0);
      float mnew[2] = {m_run[0], m_run[1]};
#pragma unroll
      for (int mt = 0; mt < 4; ++mt)
#pragma unroll
        for (int nt = 0; nt < 2; ++nt)
#pragma unroll
          for (int r = 0; r < 4; ++r) {
            float v = sacc[mt][nt][r];
            if (needmask) {
              int key = k0  + mt*16 + lg*4 + r;
              int q   = qw0 + nt*16 + l16;
              if (q < key) v = -__builtin_inff();
            }
            sacc[mt][nt][r] = v;
            mnew[nt] = fmaxf(mnew[nt], v);
          }
#pragma unroll
      for (int nt = 0; nt < 2; ++nt) {
        mnew[nt] = fmaxf(mnew[nt], __shfl_xor(mnew[nt], 16));
        mnew[nt] = fmaxf(mnew[nt], __shfl_xor(mnew[nt], 32));
      }
      float alpha[2], rsum[2];
#pragma unroll
      for (int nt = 0; nt < 2; ++nt) {
        alpha[nt] = __builtin_amdgcn_exp2f(m_run[nt] - mnew[nt]);  // first tile: exp2(-inf)=0
        m_run[nt] = mnew[nt];
        rsum[nt]  = 0.f;
      }
      // exp + pack P directly into PV A-fragments (key-permutation makes this
      // a pure in-lane repack: j=0..3 <- mt=ks, j=4..7 <- mt=ks+2)
      bf16x8 pfrag[2][2];
#pragma unroll
      for (int nt = 0; nt < 2; ++nt)
#pragma unroll
        for (int ks = 0; ks < 2; ++ks) {
          union { short s[8]; bf16x8 v; } pk;
#pragma unroll
          for (int r = 0; r < 4; ++r) {
            float e0 = __builtin_amdgcn_exp2f(sacc[ks][nt][r]     - mnew[nt]);
            float e1 = __builtin_amdgcn_exp2f(sacc[ks + 2][nt][r] - mnew[nt]);
            rsum[nt] += e0 + e1;
            pk.s[r]     = f2bf(e0);
            pk.s[4 + r] = f2bf(e1);
          }
          pfrag[nt][ks] = pk.v;
        }
#pragma unroll
      for (int nt = 0; nt < 2; ++nt) {
        rsum[nt] += __shfl_xor(rsum[nt], 16);
        rsum[nt] += __shfl_xor(rsum[nt], 32);
        l_run[nt] = l_run[nt] * alpha[nt] + rsum[nt];
      }
      // rescale O accumulator (alpha from q=l16 layout to q=lg*4+r layout)
#pragma unroll
      for (int mo = 0; mo < 2; ++mo)
#pragma unroll
        for (int r = 0; r < 4; ++r) {
          float al = __shfl(alpha[mo], lg*4 + r);
#pragma unroll
          for (int nd = 0; nd < 4; ++nd)
            oacc[mo][nd][r] *= al;
        }

      // ---- O += P * V (V^T columns are key-permuted to match pfrag) ----
#pragma unroll
      for (int ks = 0; ks < 2; ++ks) {
        bf16x8 vfrag[4];
#pragma unroll
        for (int nd = 0; nd < 4; ++nd) {
          int colr = (ks*32 + lg*8 + nd*16) & 63;   // un-rotate d-dependent rotation
          vfrag[nd] = *(const bf16x8*)(&vT[(nd*16 + l16) * KSTR + colr]);
        }
#pragma unroll
        for (int mo = 0; mo < 2; ++mo)
#pragma unroll
          for (int nd = 0; nd < 4; ++nd)
            oacc[mo][nd] = __builtin_amdgcn_mfma_f32_16x16x32_bf16(pfrag[mo][ks], vfrag[nd], oacc[mo][nd], 0, 0, 0);
      }
    }

    __syncthreads();   // all waves done reading LDS before next store phase
  }

  // ---- epilogue: O / l, f32 out ----
#pragma unroll
  for (int mo = 0; mo < 2; ++mo)
#pragma unroll
    for (int r = 0; r < 4; ++r) {
      float lv  = __shfl(l_run[mo], lg*4 + r);
      float inv = __builtin_amdgcn_rcpf(lv);
      int qrow  = qw0 + mo*16 + lg*4 + r;
#pragma unroll
      for (int nd = 0; nd < 4; ++nd)
        op[base + (long)qrow * 64 + nd*16 + l16] = oacc[mo][nd][r] * inv;
    }
}

extern "C" void kernel_launch(void* const* d_in, const int* in_sizes, int n_in,
                              void* d_out, int out_size, void* d_ws, size_t ws_size,
                              hipStream_t stream) {
  const float* q = (const float*)d_in[0];
  const float* k = (const float*)d_in[1];
  const float* v = (const float*)d_in[2];
  const int*  cm = (const int*)d_in[3];
  float* o = (float*)d_out;
  dim3 grid(S_LEN / BM, NBH);
  mea_fwd<<<grid, dim3(512, 1, 1), 0, stream>>>(q, k, v, cm, o);
}